// Round 7
// baseline (595.431 us; speedup 1.0000x reference)
//
#include <hip/hip_runtime.h>
#include <hip/hip_bf16.h>
#include <stdint.h>

#define D 1024
#define F 4096
#define E 8
#define T 8192
#define SLOT_CAP 17408   // 16384 routed slots + per-expert pad to 128
#define BM 128
#define BK 32
#define EP_STRIDE 136    // epilogue LDS row stride (shorts): +8 pad kills bank conflicts

typedef __attribute__((ext_vector_type(8))) short bf16x8;
typedef __attribute__((ext_vector_type(4))) float f32x4;
typedef __attribute__((ext_vector_type(8))) unsigned short u16x8;

__device__ __forceinline__ unsigned short f2bf(float f) {
  unsigned u = __float_as_uint(f);
  u += 0x7fffu + ((u >> 16) & 1u);
  return (unsigned short)(u >> 16);
}
__device__ __forceinline__ float bf2f(unsigned short u) {
  return __uint_as_float(((unsigned)u) << 16);
}

// 8x fp32 -> 8x bf16 (RNE) via v_cvt_pk_bf16_f32 (4 instrs, not 32 VALU ops of f2bf)
__device__ __forceinline__ u16x8 cvt8(float4 a, float4 b) {
  __hip_bfloat162 p0 = __float22bfloat162_rn(make_float2(a.x, a.y));
  __hip_bfloat162 p1 = __float22bfloat162_rn(make_float2(a.z, a.w));
  __hip_bfloat162 p2 = __float22bfloat162_rn(make_float2(b.x, b.y));
  __hip_bfloat162 p3 = __float22bfloat162_rn(make_float2(b.z, b.w));
  union { __hip_bfloat162 h[4]; u16x8 v; } u;
  u.h[0] = p0; u.h[1] = p1; u.h[2] = p2; u.h[3] = p3;
  return u.v;
}

// exact-GELU via A&S 7.1.26 erf approx (|err| <= 1.5e-7), branch-free.
__device__ __forceinline__ float gelu_f(float v) {
  float s = fabsf(v) * 0.70710678118654752f;
  float t = __builtin_amdgcn_rcpf(fmaf(0.3275911f, s, 1.0f));
  float p = fmaf(t, 1.061405429f, -1.453152027f);
  p = fmaf(t, p, 1.421413741f);
  p = fmaf(t, p, -0.284496736f);
  p = fmaf(t, p, 0.254829592f);
  p = p * t;
  float e = 1.0f - p * __expf(-s * s);   // erf(|s|)
  e = copysignf(e, v);
  return 0.5f * v * (1.0f + e);
}

// global -> LDS async copy, 16B per lane. LDS dest must be wave-uniform base + lane*16.
__device__ __forceinline__ void gload16(const void* g, void* l) {
  auto gp = (const __attribute__((address_space(1))) unsigned int*)(uintptr_t)g;
  auto lp = (__attribute__((address_space(3))) unsigned int*)(unsigned)(uintptr_t)l;
  __builtin_amdgcn_global_load_lds(gp, lp, 16, 0, 0);
}

// prep = router ONLY now (R7): 1 wave/token, fp64 accumulate so top-2 selection
// matches the fp32 reference; also emits bf16 x. The w1 cast is GONE — gemm1 reads
// w1 directly as fp32 (reg-staged cvt_pk). The w2 cast still hides under gemm1.
__global__ __launch_bounds__(256) void prep_kernel(const float* __restrict__ x,
                                                   const float* __restrict__ rw,
                                                   int* __restrict__ tok_e,
                                                   float* __restrict__ tok_p,
                                                   unsigned short* __restrict__ xg) {
  int t = blockIdx.x * 4 + (threadIdx.x >> 6);
  int lane = threadIdx.x & 63;
  const float* xp = x + (size_t)t * D;
  unsigned short* xgp = xg + (size_t)t * D;
  double acc[E];
#pragma unroll
  for (int e = 0; e < E; e++) acc[e] = 0.0;
  for (int j = 0; j < D / 64; j++) {
    float xv = xp[j * 64 + lane];
    xgp[j * 64 + lane] = f2bf(xv);
#pragma unroll
    for (int e = 0; e < E; e++) acc[e] += (double)xv * (double)rw[e * D + j * 64 + lane];
  }
#pragma unroll
  for (int e = 0; e < E; e++) {
#pragma unroll
    for (int off = 32; off >= 1; off >>= 1) acc[e] += __shfl_xor(acc[e], off, 64);
  }
  if (lane == 0) {
    double v0 = -1e300, v1 = -1e300;
    int i0 = 0, i1 = 0;
#pragma unroll
    for (int e = 0; e < E; e++) {
      double v = acc[e];
      if (v > v0) { v1 = v0; i1 = i0; v0 = v; i0 = e; }
      else if (v > v1) { v1 = v; i1 = e; }
    }
    double e1 = exp(v1 - v0);
    double s = 1.0 + e1;
    tok_e[2 * t] = i0; tok_e[2 * t + 1] = i1;
    tok_p[2 * t] = (float)(1.0 / s);
    tok_p[2 * t + 1] = (float)(e1 / s);
  }
}

// Atomic-free bucketing: 8 blocks x 1 wave. Block e computes the full histogram
// (shfl-reduced), derives offp locally, then rank-scatters its expert's entries via
// ballot+popc (deterministic), zeroes its pad region. Block 0 publishes counts/offp.
__global__ __launch_bounds__(64) void bucket_kernel(const int* __restrict__ tok_e,
                                                    int* __restrict__ perm,
                                                    int* __restrict__ slot_of,
                                                    int* __restrict__ counts,
                                                    int* __restrict__ offp) {
  const int e = blockIdx.x;
  const int lane = threadIdx.x;
  int cnt[E];
#pragma unroll
  for (int ee = 0; ee < E; ee++) cnt[ee] = 0;
  for (int idx = lane; idx < 2 * T; idx += 64) {
    int v = tok_e[idx];
#pragma unroll
    for (int ee = 0; ee < E; ee++) cnt[ee] += (v == ee) ? 1 : 0;
  }
#pragma unroll
  for (int ee = 0; ee < E; ee++) {
#pragma unroll
    for (int off = 32; off >= 1; off >>= 1) cnt[ee] += __shfl_xor(cnt[ee], off, 64);
  }
  int off_e[E + 1];
  int o = 0;
#pragma unroll
  for (int ee = 0; ee < E; ee++) { off_e[ee] = o; o += (cnt[ee] + (BM - 1)) & ~(BM - 1); }
  off_e[E] = o;
  if (e == 0 && lane == 0) {
#pragma unroll
    for (int ee = 0; ee < E; ee++) { counts[ee] = cnt[ee]; offp[ee] = off_e[ee]; }
    offp[E] = o;
  }
  int base = 0, mycnt = 0, myend = 0;
#pragma unroll
  for (int ee = 0; ee < E; ee++) {
    if (ee == e) { base = off_e[ee]; mycnt = cnt[ee]; myend = off_e[ee + 1]; }
  }
  const int pad0 = base + mycnt;
  for (int r = 0; r < 2 * T / 64; r++) {
    int idx = r * 64 + lane;
    int v = tok_e[idx];
    bool m = (v == e);
    unsigned long long mask = __ballot(m);
    int pre = __popcll(mask & ((1ull << lane) - 1ull));
    if (m) {
      int slot = base + pre;
      perm[slot] = idx >> 1;
      slot_of[idx] = slot;
    }
    base += __popcll(mask);
  }
  for (int i = pad0 + lane; i < myend; i += 64) perm[i] = 0;
}

// GEMM1: hbuf[slot][f] = gelu( x[perm[slot]] . w1[e][f] + b1[e][f] ), bf16 out
// 128x128 tile, dbuf, 4 blocks/CU. A: gload_lds from bf16 xg (unchanged).
// B (R7): read w1 DIRECTLY as fp32 — reg-stage 4x dwordx4 -> 8x cvt_pk -> 2x
// ds_write_b128 into buf cur^1 (whose readers finished at the previous barrier;
// single-barrier dbuf preserved). Removes the 402 MB w1-cast pass from prep.
// XCD-chunked (8 x 544) quarter-walk. Blocks [4352, 20736): w2 fp32->bf16 cast
// (backfills free CU slots; measured free — R6 gemm1 same dur with/without).
__global__ __launch_bounds__(256, 4) void gemm1_kernel(const unsigned short* __restrict__ xg,
                                                       const float* __restrict__ w1,
                                                       const float* __restrict__ b1,
                                                       const int* __restrict__ perm,
                                                       const int* __restrict__ offp,
                                                       const int* __restrict__ counts,
                                                       unsigned short* __restrict__ hbuf,
                                                       const float* __restrict__ w2,
                                                       unsigned short* __restrict__ w2g) {
  const int id = blockIdx.x;
  if (id >= 4352) {                              // trailing w2-cast blocks
    int i = (id - 4352) * 256 + threadIdx.x;     // [0, E*D*F/8)
    const float4* p = (const float4*)w2 + (size_t)i * 2;
    float4 a = p[0], b = p[1];
    *(u16x8*)(w2g + (size_t)i * 8) = cvt8(a, b);
    return;
  }
  const int xcd = id & 7, loc = id >> 3;        // loc in [0,544)
  const int q = loc / 136, r = loc % 136;       // 4 quarters x (17bm x 8bn)
  const int bm = xcd * 17 + (r >> 3);
  const int bn = q * 8 + (r & 7);
  const int row0 = bm * BM;
  if (row0 >= offp[E]) return;
  int e = 0;
#pragma unroll
  for (int i = 0; i < E; i++) if (row0 >= offp[i + 1]) e = i + 1;
  if (row0 >= offp[e] + counts[e]) return;  // block entirely padding

  const int tid = threadIdx.x, lane = tid & 63, w = tid >> 6;
  __shared__ __align__(16) unsigned short smem[BM * EP_STRIDE];
  unsigned short* As0 = smem;            // As[buf] = As0 + buf*4096
  unsigned short* Bs0 = smem + 8192;     // Bs[buf] = Bs0 + buf*4096

  // A staging (bf16, gload_lds): thread owns chunks tid and tid+256 of the A half.
  const unsigned short* asrc[2];
  unsigned short* adst[2];
#pragma unroll
  for (int i = 0; i < 2; i++) {
    int ch = tid + 256 * i;
    int ar = ch >> 2, ac = (ch & 3) * 8;
    asrc[i] = xg + (size_t)perm[row0 + ar] * D + ac;
    adst[i] = As0 + ch * 8;
  }
  auto stageA = [&](int k0, int buf) {
#pragma unroll
    for (int i = 0; i < 2; i++) gload16(asrc[i] + k0, adst[i] + buf * (BM * BK));
  };

  // B staging (fp32 direct): pair-slots tid and tid+256; row=slot>>2, pr=slot&3.
  // slot tid+256 = row+64, same pr -> single base, +64*D / +64*32 offsets.
  const int brow = tid >> 2, bpr = tid & 3;
  const float* bsrc = w1 + ((size_t)e * F + (size_t)bn * BM + brow) * D + bpr * 8;
  unsigned short* bdst = Bs0 + brow * 32 + bpr * 8;

  f32x4 acc[4][4] = {};
  const int wr = (w >> 1) * 64, wc = (w & 1) * 64;
  const int fr = lane & 15, fq = lane >> 4;

  // prologue: B(0) reg->cvt->LDS, A(0) async; one barrier.
  {
    float4 p0 = *(const float4*)(bsrc);
    float4 p1 = *(const float4*)(bsrc + 4);
    float4 p2 = *(const float4*)(bsrc + 64 * D);
    float4 p3 = *(const float4*)(bsrc + 64 * D + 4);
    *(u16x8*)(bdst) = cvt8(p0, p1);
    *(u16x8*)(bdst + 2048) = cvt8(p2, p3);
    stageA(0, 0);
  }
  __syncthreads();
  int cur = 0;
  for (int k0 = 0; k0 < D; k0 += BK) {
    const bool more = (k0 + BK < D);
    float4 p0, p1, p2, p3;
    if (more) {                                  // issue next-tile loads early
      p0 = *(const float4*)(bsrc + k0 + BK);
      p1 = *(const float4*)(bsrc + k0 + BK + 4);
      p2 = *(const float4*)(bsrc + 64 * D + k0 + BK);
      p3 = *(const float4*)(bsrc + 64 * D + k0 + BK + 4);
      stageA(k0 + BK, cur ^ 1);
    }
    bf16x8 a[4], b[4];
#pragma unroll
    for (int m = 0; m < 4; m++) a[m] = *(const bf16x8*)&As0[cur * 4096 + (wr + m * 16 + fr) * BK + fq * 8];
#pragma unroll
    for (int n = 0; n < 4; n++) b[n] = *(const bf16x8*)&Bs0[cur * 4096 + (wc + n * 16 + fr) * BK + fq * 8];
#pragma unroll
    for (int m = 0; m < 4; m++)
#pragma unroll
      for (int n = 0; n < 4; n++)
        acc[m][n] = __builtin_amdgcn_mfma_f32_16x16x32_bf16(a[m], b[n], acc[m][n], 0, 0, 0);
    if (more) {                                  // write-late into cur^1 (readers done)
      unsigned short* d = bdst + (cur ^ 1) * 4096;
      *(u16x8*)(d) = cvt8(p0, p1);
      *(u16x8*)(d + 2048) = cvt8(p2, p3);
    }
    __syncthreads();
    cur ^= 1;
  }

  // epilogue: bias+gelu in-register -> bf16 LDS tile -> coalesced 16B/lane stores
#pragma unroll
  for (int n = 0; n < 4; n++) {
    int cl = wc + n * 16 + fr;
    float bias = b1[e * F + bn * BM + cl];
#pragma unroll
    for (int m = 0; m < 4; m++) {
#pragma unroll
      for (int j = 0; j < 4; j++) {
        int rl = wr + m * 16 + fq * 4 + j;
        smem[rl * EP_STRIDE + cl] = f2bf(gelu_f(acc[m][n][j] + bias));
      }
    }
  }
  __syncthreads();
#pragma unroll
  for (int i = 0; i < 8; i++) {
    int idx = tid + i * 256;          // 2048 16B-chunks: 128 rows x 16
    int r2 = idx >> 4, c = (idx & 15) * 8;
    u16x8 v = *(const u16x8*)&smem[r2 * EP_STRIDE + c];
    *(u16x8*)&hbuf[(size_t)(row0 + r2) * F + bn * BM + c] = v;
  }
}

// GEMM2 (K-split-2): ypart[ks][slot][d] = h[slot][ks*2048:+2048].w2[e][d][same] (+b2 if ks==0)
// 128x128 tile, dbuf, 4 blocks/CU. Grid 2176 = 8bn x 2ks x 136bm = 8*272.
__global__ __launch_bounds__(256, 4) void gemm2_kernel(const unsigned short* __restrict__ hbuf,
                                                       const unsigned short* __restrict__ w2g,
                                                       const float* __restrict__ b2,
                                                       const int* __restrict__ offp,
                                                       const int* __restrict__ counts,
                                                       unsigned short* __restrict__ ypart) {
  const int id = blockIdx.x;
  const int swz = (id & 7) * 272 + (id >> 3);   // bijective (2176=8*272)
  const int bn = swz & 7;                        // bn fastest -> share A panel
  const int ks = (swz >> 3) & 1;
  const int bm = swz >> 4;
  const int row0 = bm * BM;
  if (row0 >= offp[E]) return;
  int e = 0;
#pragma unroll
  for (int i = 0; i < E; i++) if (row0 >= offp[i + 1]) e = i + 1;
  const int valid_end = offp[e] + counts[e];
  if (row0 >= valid_end) return;

  const int tid = threadIdx.x, lane = tid & 63, w = tid >> 6;
  __shared__ __align__(16) unsigned short smem[BM * EP_STRIDE];
  unsigned short* As0 = smem;
  unsigned short* Bs0 = smem + 8192;

  const int kbase = ks * (F / 2);
  const unsigned short* gsrc[4];
  unsigned short* ldst[4];
#pragma unroll
  for (int i = 0; i < 4; i++) {
    int ch = tid + 256 * i;
    if (ch < 512) {
      int ar = ch >> 2, ac = (ch & 3) * 8;
      gsrc[i] = hbuf + (size_t)(row0 + ar) * F + kbase + ac;
      ldst[i] = As0 + ch * 8;
    } else {
      int c = ch - 512;
      int br = c >> 2, bc = (c & 3) * 8;
      gsrc[i] = w2g + ((size_t)e * D + (size_t)bn * BM + br) * F + kbase + bc;
      ldst[i] = Bs0 + c * 8;
    }
  }
  auto stage = [&](int k0, int buf) {
#pragma unroll
    for (int i = 0; i < 4; i++) gload16(gsrc[i] + k0, ldst[i] + buf * (BM * BK));
  };

  f32x4 acc[4][4] = {};
  const int wr = (w >> 1) * 64, wc = (w & 1) * 64;
  const int fr = lane & 15, fq = lane >> 4;

  stage(0, 0);
  __syncthreads();
  int cur = 0;
  for (int k0 = 0; k0 < F / 2; k0 += BK) {
    if (k0 + BK < F / 2) stage(k0 + BK, cur ^ 1);
    bf16x8 a[4], b[4];
#pragma unroll
    for (int m = 0; m < 4; m++) a[m] = *(const bf16x8*)&As0[cur * 4096 + (wr + m * 16 + fr) * BK + fq * 8];
#pragma unroll
    for (int n = 0; n < 4; n++) b[n] = *(const bf16x8*)&Bs0[cur * 4096 + (wc + n * 16 + fr) * BK + fq * 8];
#pragma unroll
    for (int m = 0; m < 4; m++)
#pragma unroll
      for (int n = 0; n < 4; n++)
        acc[m][n] = __builtin_amdgcn_mfma_f32_16x16x32_bf16(a[m], b[n], acc[m][n], 0, 0, 0);
    __syncthreads();
    cur ^= 1;
  }

  // epilogue via LDS (full-line coalesced stores)
#pragma unroll
  for (int n = 0; n < 4; n++) {
    int cl = wc + n * 16 + fr;
    float bias = (ks == 0) ? b2[e * D + bn * BM + cl] : 0.0f;
#pragma unroll
    for (int m = 0; m < 4; m++) {
#pragma unroll
      for (int j = 0; j < 4; j++) {
        int rl = wr + m * 16 + fq * 4 + j;
        smem[rl * EP_STRIDE + cl] = f2bf(acc[m][n][j] + bias);
      }
    }
  }
  __syncthreads();
  unsigned short* ybase = ypart + (size_t)ks * SLOT_CAP * D;
#pragma unroll
  for (int i = 0; i < 8; i++) {
    int idx = tid + i * 256;
    int r2 = idx >> 4, c = (idx & 15) * 8;
    if (row0 + r2 < valid_end) {
      u16x8 v = *(const u16x8*)&smem[r2 * EP_STRIDE + c];
      *(u16x8*)&ybase[(size_t)(row0 + r2) * D + bn * BM + c] = v;
    }
  }
}

// out[t][d] = g0*(p0[s0]+p1[s0]) + g1*(p0[s1]+p1[s1])   (full overwrite -> no memset)
__global__ __launch_bounds__(256) void combine_kernel(const unsigned short* __restrict__ ypart,
                                                      const int* __restrict__ slot_of,
                                                      const float* __restrict__ tok_p,
                                                      float* __restrict__ out) {
  int i = blockIdx.x * 256 + threadIdx.x;   // indexes 8-elem groups
  int t = i >> 7;                            // D/8 = 128 groups per token
  int g8 = i & 127;
  int s0 = slot_of[2 * t], s1 = slot_of[2 * t + 1];
  float g0 = tok_p[2 * t], g1 = tok_p[2 * t + 1];
  const unsigned short* p0 = ypart;
  const unsigned short* p1 = ypart + (size_t)SLOT_CAP * D;
  u16x8 a0 = *(const u16x8*)(p0 + (size_t)s0 * D + g8 * 8);
  u16x8 b0 = *(const u16x8*)(p1 + (size_t)s0 * D + g8 * 8);
  u16x8 a1 = *(const u16x8*)(p0 + (size_t)s1 * D + g8 * 8);
  u16x8 b1 = *(const u16x8*)(p1 + (size_t)s1 * D + g8 * 8);
  float o[8];
#pragma unroll
  for (int j = 0; j < 8; j++)
    o[j] = g0 * (bf2f(a0[j]) + bf2f(b0[j])) + g1 * (bf2f(a1[j]) + bf2f(b1[j]));
  float4* op = (float4*)(out + (size_t)t * D + g8 * 8);
  op[0] = make_float4(o[0], o[1], o[2], o[3]);
  op[1] = make_float4(o[4], o[5], o[6], o[7]);
}

extern "C" void kernel_launch(void* const* d_in, const int* in_sizes, int n_in,
                              void* d_out, int out_size, void* d_ws, size_t ws_size,
                              hipStream_t stream) {
  const float* x = (const float*)d_in[0];
  const float* rw = (const float*)d_in[1];
  const float* w1 = (const float*)d_in[2];
  const float* b1 = (const float*)d_in[3];
  const float* w2 = (const float*)d_in[4];
  const float* b2 = (const float*)d_in[5];
  float* out = (float*)d_out;

  char* ws = (char*)d_ws;
  size_t off = 0;
  auto alloc = [&](size_t bytes) {
    void* p = ws + off;
    off = (off + bytes + 255) & ~(size_t)255;
    return p;
  };
  int* counts = (int*)alloc(E * 4);
  int* offp = (int*)alloc((E + 1) * 4);
  int* tok_e = (int*)alloc((size_t)T * 2 * 4);
  float* tok_p = (float*)alloc((size_t)T * 2 * 4);
  int* perm = (int*)alloc((size_t)SLOT_CAP * 4);
  int* slot_of = (int*)alloc((size_t)T * 2 * 4);
  unsigned short* xg = (unsigned short*)alloc((size_t)T * D * 2);        // 16.8 MB
  unsigned short* ydead = (unsigned short*)alloc((size_t)E * F * D * 2); // 67 MB (ypart alias room; was w1g)
  unsigned short* w2g = (unsigned short*)alloc((size_t)E * D * F * 2);   // 67 MB
  unsigned short* hbuf = (unsigned short*)alloc((size_t)SLOT_CAP * F * 2); // 143 MB
  // ypart: 2 bf16 partial buffers, 71.3 MB, aliased over xg(16.8)+ydead(67)
  // (xg dead after gemm1; re-written by prep every call -> deterministic).
  unsigned short* ypart = xg;
  (void)ydead; (void)ws_size; (void)in_sizes; (void)n_in; (void)out_size;

  hipLaunchKernelGGL(prep_kernel, dim3(2048), dim3(256), 0, stream,
                     x, rw, tok_e, tok_p, xg);
  hipLaunchKernelGGL(bucket_kernel, dim3(E), dim3(64), 0, stream,
                     tok_e, perm, slot_of, counts, offp);
  hipLaunchKernelGGL(gemm1_kernel, dim3(4352 + E * D * F / 8 / 256), dim3(256), 0, stream,
                     xg, w1, b1, perm, offp, counts, hbuf, w2, w2g);
  hipLaunchKernelGGL(gemm2_kernel, dim3(2176), dim3(256), 0, stream,
                     hbuf, w2g, b2, offp, counts, ypart);
  hipLaunchKernelGGL(combine_kernel, dim3(T * D / 8 / 256), dim3(256), 0, stream,
                     ypart, slot_of, tok_p, out);
}

// Round 8
// 588.400 us; speedup vs baseline: 1.0119x; 1.0119x over previous
//
#include <hip/hip_runtime.h>
#include <hip/hip_bf16.h>
#include <stdint.h>

#define D 1024
#define F 4096
#define E 8
#define T 8192
#define SLOT_CAP 17408   // 16384 routed slots + per-expert pad to 128
#define BM 128
#define BK 32
#define EP_STRIDE 136    // epilogue LDS row stride (shorts): +8 pad kills bank conflicts

typedef __attribute__((ext_vector_type(8))) short bf16x8;
typedef __attribute__((ext_vector_type(4))) float f32x4;
typedef __attribute__((ext_vector_type(8))) unsigned short u16x8;

__device__ __forceinline__ unsigned short f2bf(float f) {
  unsigned u = __float_as_uint(f);
  u += 0x7fffu + ((u >> 16) & 1u);
  return (unsigned short)(u >> 16);
}
__device__ __forceinline__ float bf2f(unsigned short u) {
  return __uint_as_float(((unsigned)u) << 16);
}

// exact-GELU via A&S 7.1.26 erf approx (|err| <= 1.5e-7), branch-free.
__device__ __forceinline__ float gelu_f(float v) {
  float s = fabsf(v) * 0.70710678118654752f;
  float t = __builtin_amdgcn_rcpf(fmaf(0.3275911f, s, 1.0f));
  float p = fmaf(t, 1.061405429f, -1.453152027f);
  p = fmaf(t, p, 1.421413741f);
  p = fmaf(t, p, -0.284496736f);
  p = fmaf(t, p, 0.254829592f);
  p = p * t;
  float e = 1.0f - p * __expf(-s * s);   // erf(|s|)
  e = copysignf(e, v);
  return 0.5f * v * (1.0f + e);
}

// global -> LDS async copy, 16B per lane. LDS dest must be wave-uniform base + lane*16.
__device__ __forceinline__ void gload16(const void* g, void* l) {
  auto gp = (const __attribute__((address_space(1))) unsigned int*)(uintptr_t)g;
  auto lp = (__attribute__((address_space(3))) unsigned int*)(unsigned)(uintptr_t)l;
  __builtin_amdgcn_global_load_lds(gp, lp, 16, 0, 0);
}

// Merged prep: blocks [0,2048) = router (1 wave/token, fp64 accumulate so top-2
// selection matches the fp32 reference; also emits bf16 x). Blocks [2048,18432) =
// fp32->bf16 cast of w1 ONLY. The w2 cast hides under gemm1 (measured free, R6).
// R7 lesson: gemm1 consuming w1 as fp32 directly costs MORE than this serial cast
// (+86 us: doubled B fetch + reg-staging latency). The cast stays.
__global__ __launch_bounds__(256) void prep_kernel(const float* __restrict__ x,
                                                   const float* __restrict__ rw,
                                                   const float* __restrict__ w1,
                                                   int* __restrict__ tok_e,
                                                   float* __restrict__ tok_p,
                                                   unsigned short* __restrict__ xg,
                                                   unsigned short* __restrict__ w1g) {
  if (blockIdx.x >= 2048) {
    int i = (blockIdx.x - 2048) * 256 + threadIdx.x;   // [0, E*F*D/8)
    const float4* p = (const float4*)w1 + (size_t)i * 2;
    float4 a = p[0], b = p[1];
    u16x8 o;
    o[0] = f2bf(a.x); o[1] = f2bf(a.y); o[2] = f2bf(a.z); o[3] = f2bf(a.w);
    o[4] = f2bf(b.x); o[5] = f2bf(b.y); o[6] = f2bf(b.z); o[7] = f2bf(b.w);
    *(u16x8*)(w1g + (size_t)i * 8) = o;
    return;
  }
  int t = blockIdx.x * 4 + (threadIdx.x >> 6);
  int lane = threadIdx.x & 63;
  const float* xp = x + (size_t)t * D;
  unsigned short* xgp = xg + (size_t)t * D;
  double acc[E];
#pragma unroll
  for (int e = 0; e < E; e++) acc[e] = 0.0;
  for (int j = 0; j < D / 64; j++) {
    float xv = xp[j * 64 + lane];
    xgp[j * 64 + lane] = f2bf(xv);
#pragma unroll
    for (int e = 0; e < E; e++) acc[e] += (double)xv * (double)rw[e * D + j * 64 + lane];
  }
#pragma unroll
  for (int e = 0; e < E; e++) {
#pragma unroll
    for (int off = 32; off >= 1; off >>= 1) acc[e] += __shfl_xor(acc[e], off, 64);
  }
  if (lane == 0) {
    double v0 = -1e300, v1 = -1e300;
    int i0 = 0, i1 = 0;
#pragma unroll
    for (int e = 0; e < E; e++) {
      double v = acc[e];
      if (v > v0) { v1 = v0; i1 = i0; v0 = v; i0 = e; }
      else if (v > v1) { v1 = v; i1 = e; }
    }
    double e1 = exp(v1 - v0);
    double s = 1.0 + e1;
    tok_e[2 * t] = i0; tok_e[2 * t + 1] = i1;
    tok_p[2 * t] = (float)(1.0 / s);
    tok_p[2 * t + 1] = (float)(e1 / s);
  }
}

// Atomic-free bucketing: 8 blocks x 1 wave. Block e computes the full histogram
// (shfl-reduced), derives offp locally, then rank-scatters its expert's entries via
// ballot+popc (deterministic), zeroes its pad region. Block 0 publishes counts/offp.
__global__ __launch_bounds__(64) void bucket_kernel(const int* __restrict__ tok_e,
                                                    int* __restrict__ perm,
                                                    int* __restrict__ slot_of,
                                                    int* __restrict__ counts,
                                                    int* __restrict__ offp) {
  const int e = blockIdx.x;
  const int lane = threadIdx.x;
  int cnt[E];
#pragma unroll
  for (int ee = 0; ee < E; ee++) cnt[ee] = 0;
  for (int idx = lane; idx < 2 * T; idx += 64) {
    int v = tok_e[idx];
#pragma unroll
    for (int ee = 0; ee < E; ee++) cnt[ee] += (v == ee) ? 1 : 0;
  }
#pragma unroll
  for (int ee = 0; ee < E; ee++) {
#pragma unroll
    for (int off = 32; off >= 1; off >>= 1) cnt[ee] += __shfl_xor(cnt[ee], off, 64);
  }
  int off_e[E + 1];
  int o = 0;
#pragma unroll
  for (int ee = 0; ee < E; ee++) { off_e[ee] = o; o += (cnt[ee] + (BM - 1)) & ~(BM - 1); }
  off_e[E] = o;
  if (e == 0 && lane == 0) {
#pragma unroll
    for (int ee = 0; ee < E; ee++) { counts[ee] = cnt[ee]; offp[ee] = off_e[ee]; }
    offp[E] = o;
  }
  int base = 0, mycnt = 0, myend = 0;
#pragma unroll
  for (int ee = 0; ee < E; ee++) {
    if (ee == e) { base = off_e[ee]; mycnt = cnt[ee]; myend = off_e[ee + 1]; }
  }
  const int pad0 = base + mycnt;
  for (int r = 0; r < 2 * T / 64; r++) {
    int idx = r * 64 + lane;
    int v = tok_e[idx];
    bool m = (v == e);
    unsigned long long mask = __ballot(m);
    int pre = __popcll(mask & ((1ull << lane) - 1ull));
    if (m) {
      int slot = base + pre;
      perm[slot] = idx >> 1;
      slot_of[idx] = slot;
    }
    base += __popcll(mask);
  }
  for (int i = pad0 + lane; i < myend; i += 64) perm[i] = 0;
}

// GEMM1 (R6-proven): hbuf[slot][f] = gelu( x[perm[slot]] . w1[e][f] + b1[e][f] )
// 128x128 tile, dbuf, 4 blocks/CU (launch_bounds(256,4) -> VGPR 64, verified).
// XCD-chunked (8 x 544) quarter-walk. Blocks [4352, 20736): w2 fp32->bf16 cast
// (backfills free CU slots + drain tail; measured free in R6).
__global__ __launch_bounds__(256, 4) void gemm1_kernel(const unsigned short* __restrict__ xg,
                                                       const unsigned short* __restrict__ w1g,
                                                       const float* __restrict__ b1,
                                                       const int* __restrict__ perm,
                                                       const int* __restrict__ offp,
                                                       const int* __restrict__ counts,
                                                       unsigned short* __restrict__ hbuf,
                                                       const float* __restrict__ w2,
                                                       unsigned short* __restrict__ w2g) {
  const int id = blockIdx.x;
  if (id >= 4352) {                              // trailing w2-cast blocks
    int i = (id - 4352) * 256 + threadIdx.x;     // [0, E*D*F/8)
    const float4* p = (const float4*)w2 + (size_t)i * 2;
    float4 a = p[0], b = p[1];
    u16x8 o;
    o[0] = f2bf(a.x); o[1] = f2bf(a.y); o[2] = f2bf(a.z); o[3] = f2bf(a.w);
    o[4] = f2bf(b.x); o[5] = f2bf(b.y); o[6] = f2bf(b.z); o[7] = f2bf(b.w);
    *(u16x8*)(w2g + (size_t)i * 8) = o;
    return;
  }
  const int xcd = id & 7, loc = id >> 3;        // loc in [0,544)
  const int q = loc / 136, r = loc % 136;       // 4 quarters x (17bm x 8bn)
  const int bm = xcd * 17 + (r >> 3);
  const int bn = q * 8 + (r & 7);
  const int row0 = bm * BM;
  if (row0 >= offp[E]) return;
  int e = 0;
#pragma unroll
  for (int i = 0; i < E; i++) if (row0 >= offp[i + 1]) e = i + 1;
  if (row0 >= offp[e] + counts[e]) return;  // block entirely padding

  const int tid = threadIdx.x, lane = tid & 63, w = tid >> 6;
  __shared__ __align__(16) unsigned short smem[BM * EP_STRIDE];
  unsigned short* As0 = smem;            // As[buf] = As0 + buf*4096
  unsigned short* Bs0 = smem + 8192;     // Bs[buf] = Bs0 + buf*4096

  const unsigned short* gsrc[4];
  unsigned short* ldst[4];
#pragma unroll
  for (int i = 0; i < 4; i++) {
    int ch = tid + 256 * i;
    if (ch < 512) {
      int ar = ch >> 2, ac = (ch & 3) * 8;
      gsrc[i] = xg + (size_t)perm[row0 + ar] * D + ac;
      ldst[i] = As0 + ch * 8;
    } else {
      int c = ch - 512;
      int br = c >> 2, bc = (c & 3) * 8;
      gsrc[i] = w1g + ((size_t)e * F + (size_t)bn * BM + br) * D + bc;
      ldst[i] = Bs0 + c * 8;
    }
  }
  auto stage = [&](int k0, int buf) {
#pragma unroll
    for (int i = 0; i < 4; i++) gload16(gsrc[i] + k0, ldst[i] + buf * (BM * BK));
  };

  f32x4 acc[4][4] = {};
  const int wr = (w >> 1) * 64, wc = (w & 1) * 64;
  const int fr = lane & 15, fq = lane >> 4;

  stage(0, 0);
  __syncthreads();
  int cur = 0;
  for (int k0 = 0; k0 < D; k0 += BK) {
    if (k0 + BK < D) stage(k0 + BK, cur ^ 1);   // prefetch flies during compute
    bf16x8 a[4], b[4];
#pragma unroll
    for (int m = 0; m < 4; m++) a[m] = *(const bf16x8*)&As0[cur * 4096 + (wr + m * 16 + fr) * BK + fq * 8];
#pragma unroll
    for (int n = 0; n < 4; n++) b[n] = *(const bf16x8*)&Bs0[cur * 4096 + (wc + n * 16 + fr) * BK + fq * 8];
#pragma unroll
    for (int m = 0; m < 4; m++)
#pragma unroll
      for (int n = 0; n < 4; n++)
        acc[m][n] = __builtin_amdgcn_mfma_f32_16x16x32_bf16(a[m], b[n], acc[m][n], 0, 0, 0);
    __syncthreads();
    cur ^= 1;
  }

  // epilogue: bias+gelu in-register -> bf16 LDS tile -> coalesced 16B/lane stores
#pragma unroll
  for (int n = 0; n < 4; n++) {
    int cl = wc + n * 16 + fr;
    float bias = b1[e * F + bn * BM + cl];
#pragma unroll
    for (int m = 0; m < 4; m++) {
#pragma unroll
      for (int j = 0; j < 4; j++) {
        int rl = wr + m * 16 + fq * 4 + j;
        smem[rl * EP_STRIDE + cl] = f2bf(gelu_f(acc[m][n][j] + bias));
      }
    }
  }
  __syncthreads();
#pragma unroll
  for (int i = 0; i < 8; i++) {
    int idx = tid + i * 256;          // 2048 16B-chunks: 128 rows x 16
    int r2 = idx >> 4, c = (idx & 15) * 8;
    u16x8 v = *(const u16x8*)&smem[r2 * EP_STRIDE + c];
    *(u16x8*)&hbuf[(size_t)(row0 + r2) * F + bn * BM + c] = v;
  }
}

// GEMM2 (R8: K-split-4): ypart[ks][slot][d] = h[slot][ks*1024:+1024].w2[e][d][same]
// (+b2 if ks==0). 128x128 tile, dbuf, 4 blocks/CU. Grid 4352 = 8 XCD x 544
// (bn fastest -> A-panel share; 136bm x 4ks x 8bn). Halves block latency (~95->~50us)
// so the un-backfilled drain tail halves (gemm2 has no cast blocks to fill it).
__global__ __launch_bounds__(256, 4) void gemm2_kernel(const unsigned short* __restrict__ hbuf,
                                                       const unsigned short* __restrict__ w2g,
                                                       const float* __restrict__ b2,
                                                       const int* __restrict__ offp,
                                                       const int* __restrict__ counts,
                                                       unsigned short* __restrict__ ypart) {
  const int id = blockIdx.x;
  const int swz = (id & 7) * 544 + (id >> 3);   // bijective (4352=8*544)
  const int bn = swz & 7;                        // bn fastest -> share A panel
  const int ks = (swz >> 3) & 3;
  const int bm = swz >> 5;                       // [0,136)
  const int row0 = bm * BM;
  if (row0 >= offp[E]) return;
  int e = 0;
#pragma unroll
  for (int i = 0; i < E; i++) if (row0 >= offp[i + 1]) e = i + 1;
  const int valid_end = offp[e] + counts[e];
  if (row0 >= valid_end) return;

  const int tid = threadIdx.x, lane = tid & 63, w = tid >> 6;
  __shared__ __align__(16) unsigned short smem[BM * EP_STRIDE];
  unsigned short* As0 = smem;
  unsigned short* Bs0 = smem + 8192;

  const int kbase = ks * (F / 4);
  const unsigned short* gsrc[4];
  unsigned short* ldst[4];
#pragma unroll
  for (int i = 0; i < 4; i++) {
    int ch = tid + 256 * i;
    if (ch < 512) {
      int ar = ch >> 2, ac = (ch & 3) * 8;
      gsrc[i] = hbuf + (size_t)(row0 + ar) * F + kbase + ac;
      ldst[i] = As0 + ch * 8;
    } else {
      int c = ch - 512;
      int br = c >> 2, bc = (c & 3) * 8;
      gsrc[i] = w2g + ((size_t)e * D + (size_t)bn * BM + br) * F + kbase + bc;
      ldst[i] = Bs0 + c * 8;
    }
  }
  auto stage = [&](int k0, int buf) {
#pragma unroll
    for (int i = 0; i < 4; i++) gload16(gsrc[i] + k0, ldst[i] + buf * (BM * BK));
  };

  f32x4 acc[4][4] = {};
  const int wr = (w >> 1) * 64, wc = (w & 1) * 64;
  const int fr = lane & 15, fq = lane >> 4;

  stage(0, 0);
  __syncthreads();
  int cur = 0;
  for (int k0 = 0; k0 < F / 4; k0 += BK) {
    if (k0 + BK < F / 4) stage(k0 + BK, cur ^ 1);
    bf16x8 a[4], b[4];
#pragma unroll
    for (int m = 0; m < 4; m++) a[m] = *(const bf16x8*)&As0[cur * 4096 + (wr + m * 16 + fr) * BK + fq * 8];
#pragma unroll
    for (int n = 0; n < 4; n++) b[n] = *(const bf16x8*)&Bs0[cur * 4096 + (wc + n * 16 + fr) * BK + fq * 8];
#pragma unroll
    for (int m = 0; m < 4; m++)
#pragma unroll
      for (int n = 0; n < 4; n++)
        acc[m][n] = __builtin_amdgcn_mfma_f32_16x16x32_bf16(a[m], b[n], acc[m][n], 0, 0, 0);
    __syncthreads();
    cur ^= 1;
  }

  // epilogue via LDS (full-line coalesced stores)
#pragma unroll
  for (int n = 0; n < 4; n++) {
    int cl = wc + n * 16 + fr;
    float bias = (ks == 0) ? b2[e * D + bn * BM + cl] : 0.0f;
#pragma unroll
    for (int m = 0; m < 4; m++) {
#pragma unroll
      for (int j = 0; j < 4; j++) {
        int rl = wr + m * 16 + fq * 4 + j;
        smem[rl * EP_STRIDE + cl] = f2bf(acc[m][n][j] + bias);
      }
    }
  }
  __syncthreads();
  unsigned short* ybase = ypart + (size_t)ks * SLOT_CAP * D;
#pragma unroll
  for (int i = 0; i < 8; i++) {
    int idx = tid + i * 256;
    int r2 = idx >> 4, c = (idx & 15) * 8;
    if (row0 + r2 < valid_end) {
      u16x8 v = *(const u16x8*)&smem[r2 * EP_STRIDE + c];
      *(u16x8*)&ybase[(size_t)(row0 + r2) * D + bn * BM + c] = v;
    }
  }
}

// out[t][d] = g0*sum_ks(y[ks][s0]) + g1*sum_ks(y[ks][s1])   (full overwrite, 4 parts)
__global__ __launch_bounds__(256) void combine_kernel(const unsigned short* __restrict__ ypart,
                                                      const int* __restrict__ slot_of,
                                                      const float* __restrict__ tok_p,
                                                      float* __restrict__ out) {
  int i = blockIdx.x * 256 + threadIdx.x;   // indexes 8-elem groups
  int t = i >> 7;                            // D/8 = 128 groups per token
  int g8 = i & 127;
  int s0 = slot_of[2 * t], s1 = slot_of[2 * t + 1];
  float g0 = tok_p[2 * t], g1 = tok_p[2 * t + 1];
  float o[8];
#pragma unroll
  for (int j = 0; j < 8; j++) o[j] = 0.0f;
#pragma unroll
  for (int p = 0; p < 4; p++) {
    const unsigned short* pp = ypart + (size_t)p * SLOT_CAP * D;
    u16x8 va = *(const u16x8*)(pp + (size_t)s0 * D + g8 * 8);
    u16x8 vb = *(const u16x8*)(pp + (size_t)s1 * D + g8 * 8);
#pragma unroll
    for (int j = 0; j < 8; j++) o[j] += g0 * bf2f(va[j]) + g1 * bf2f(vb[j]);
  }
  float4* op = (float4*)(out + (size_t)t * D + g8 * 8);
  op[0] = make_float4(o[0], o[1], o[2], o[3]);
  op[1] = make_float4(o[4], o[5], o[6], o[7]);
}

extern "C" void kernel_launch(void* const* d_in, const int* in_sizes, int n_in,
                              void* d_out, int out_size, void* d_ws, size_t ws_size,
                              hipStream_t stream) {
  const float* x = (const float*)d_in[0];
  const float* rw = (const float*)d_in[1];
  const float* w1 = (const float*)d_in[2];
  const float* b1 = (const float*)d_in[3];
  const float* w2 = (const float*)d_in[4];
  const float* b2 = (const float*)d_in[5];
  float* out = (float*)d_out;

  char* ws = (char*)d_ws;
  size_t off = 0;
  auto alloc = [&](size_t bytes) {
    void* p = ws + off;
    off = (off + bytes + 255) & ~(size_t)255;
    return p;
  };
  int* counts = (int*)alloc(E * 4);
  int* offp = (int*)alloc((E + 1) * 4);
  int* tok_e = (int*)alloc((size_t)T * 2 * 4);
  float* tok_p = (float*)alloc((size_t)T * 2 * 4);
  int* perm = (int*)alloc((size_t)SLOT_CAP * 4);
  int* slot_of = (int*)alloc((size_t)T * 2 * 4);
  unsigned short* xg = (unsigned short*)alloc((size_t)T * D * 2);        // 16.8 MB
  unsigned short* w1g = (unsigned short*)alloc((size_t)E * F * D * 2);   // 67 MB
  unsigned short* w2g = (unsigned short*)alloc((size_t)E * D * F * 2);   // 67 MB
  unsigned short* hbuf = (unsigned short*)alloc((size_t)SLOT_CAP * F * 2); // 143 MB
  // ypart: 4 bf16 partial buffers (K-split-4), 142.6 MB contiguous. Total ws ~437 MB.
  unsigned short* ypart = (unsigned short*)alloc((size_t)4 * SLOT_CAP * D * 2);
  (void)ws_size; (void)in_sizes; (void)n_in; (void)out_size;

  hipLaunchKernelGGL(prep_kernel, dim3(2048 + E * F * D / 8 / 256), dim3(256), 0, stream,
                     x, rw, w1, tok_e, tok_p, xg, w1g);
  hipLaunchKernelGGL(bucket_kernel, dim3(E), dim3(64), 0, stream,
                     tok_e, perm, slot_of, counts, offp);
  hipLaunchKernelGGL(gemm1_kernel, dim3(4352 + E * D * F / 8 / 256), dim3(256), 0, stream,
                     xg, w1g, b1, perm, offp, counts, hbuf, w2, w2g);
  hipLaunchKernelGGL(gemm2_kernel, dim3(4352), dim3(256), 0, stream,
                     hbuf, w2g, b2, offp, counts, ypart);
  hipLaunchKernelGGL(combine_kernel, dim3(T * D / 8 / 256), dim3(256), 0, stream,
                     ypart, slot_of, tok_p, out);
}

// Round 9
// 553.881 us; speedup vs baseline: 1.0750x; 1.0623x over previous
//
#include <hip/hip_runtime.h>
#include <hip/hip_bf16.h>
#include <stdint.h>

#define D 1024
#define F 4096
#define E 8
#define T 8192
#define SLOT_CAP 17408   // 16384 routed slots + per-expert pad to 128
#define BM 128
#define BK 32
#define EP_STRIDE 136    // epilogue LDS row stride (shorts): +8 pad kills bank conflicts

typedef __attribute__((ext_vector_type(8))) short bf16x8;
typedef __attribute__((ext_vector_type(4))) float f32x4;
typedef __attribute__((ext_vector_type(8))) unsigned short u16x8;

__device__ __forceinline__ unsigned short f2bf(float f) {
  unsigned u = __float_as_uint(f);
  u += 0x7fffu + ((u >> 16) & 1u);
  return (unsigned short)(u >> 16);
}
__device__ __forceinline__ float bf2f(unsigned short u) {
  return __uint_as_float(((unsigned)u) << 16);
}

// exact-GELU via A&S 7.1.26 erf approx (|err| <= 1.5e-7), branch-free.
__device__ __forceinline__ float gelu_f(float v) {
  float s = fabsf(v) * 0.70710678118654752f;
  float t = __builtin_amdgcn_rcpf(fmaf(0.3275911f, s, 1.0f));
  float p = fmaf(t, 1.061405429f, -1.453152027f);
  p = fmaf(t, p, 1.421413741f);
  p = fmaf(t, p, -0.284496736f);
  p = fmaf(t, p, 0.254829592f);
  p = p * t;
  float e = 1.0f - p * __expf(-s * s);   // erf(|s|)
  e = copysignf(e, v);
  return 0.5f * v * (1.0f + e);
}

// global -> LDS async copy, 16B per lane. LDS dest must be wave-uniform base + lane*16.
__device__ __forceinline__ void gload16(const void* g, void* l) {
  auto gp = (const __attribute__((address_space(1))) unsigned int*)(uintptr_t)g;
  auto lp = (__attribute__((address_space(3))) unsigned int*)(unsigned)(uintptr_t)l;
  __builtin_amdgcn_global_load_lds(gp, lp, 16, 0, 0);
}

// Merged prep: blocks [0,2048) = router (1 wave/token, fp64 accumulate so top-2
// selection matches the fp32 reference; also emits bf16 x). Blocks [2048,18432) =
// fp32->bf16 cast of w1 ONLY. The w2 cast is deferred into gemm1's launch (it is
// not needed until gemm2) so its ~200 MB of traffic hides under gemm1 compute.
// R7 lesson: gemm1 consuming w1 as fp32 directly costs MORE than this serial cast.
__global__ __launch_bounds__(256) void prep_kernel(const float* __restrict__ x,
                                                   const float* __restrict__ rw,
                                                   const float* __restrict__ w1,
                                                   int* __restrict__ tok_e,
                                                   float* __restrict__ tok_p,
                                                   unsigned short* __restrict__ xg,
                                                   unsigned short* __restrict__ w1g) {
  if (blockIdx.x >= 2048) {
    int i = (blockIdx.x - 2048) * 256 + threadIdx.x;   // [0, E*F*D/8)
    const float4* p = (const float4*)w1 + (size_t)i * 2;
    float4 a = p[0], b = p[1];
    u16x8 o;
    o[0] = f2bf(a.x); o[1] = f2bf(a.y); o[2] = f2bf(a.z); o[3] = f2bf(a.w);
    o[4] = f2bf(b.x); o[5] = f2bf(b.y); o[6] = f2bf(b.z); o[7] = f2bf(b.w);
    *(u16x8*)(w1g + (size_t)i * 8) = o;
    return;
  }
  int t = blockIdx.x * 4 + (threadIdx.x >> 6);
  int lane = threadIdx.x & 63;
  const float* xp = x + (size_t)t * D;
  unsigned short* xgp = xg + (size_t)t * D;
  double acc[E];
#pragma unroll
  for (int e = 0; e < E; e++) acc[e] = 0.0;
  for (int j = 0; j < D / 64; j++) {
    float xv = xp[j * 64 + lane];
    xgp[j * 64 + lane] = f2bf(xv);
#pragma unroll
    for (int e = 0; e < E; e++) acc[e] += (double)xv * (double)rw[e * D + j * 64 + lane];
  }
#pragma unroll
  for (int e = 0; e < E; e++) {
#pragma unroll
    for (int off = 32; off >= 1; off >>= 1) acc[e] += __shfl_xor(acc[e], off, 64);
  }
  if (lane == 0) {
    double v0 = -1e300, v1 = -1e300;
    int i0 = 0, i1 = 0;
#pragma unroll
    for (int e = 0; e < E; e++) {
      double v = acc[e];
      if (v > v0) { v1 = v0; i1 = i0; v0 = v; i0 = e; }
      else if (v > v1) { v1 = v; i1 = e; }
    }
    double e1 = exp(v1 - v0);
    double s = 1.0 + e1;
    tok_e[2 * t] = i0; tok_e[2 * t + 1] = i1;
    tok_p[2 * t] = (float)(1.0 / s);
    tok_p[2 * t + 1] = (float)(e1 / s);
  }
}

// Atomic-free bucketing: 8 blocks x 1 wave. Block e computes the full histogram
// (shfl-reduced), derives offp locally, then rank-scatters its expert's entries via
// ballot+popc (deterministic), zeroes its pad region. Block 0 publishes counts/offp.
__global__ __launch_bounds__(64) void bucket_kernel(const int* __restrict__ tok_e,
                                                    int* __restrict__ perm,
                                                    int* __restrict__ slot_of,
                                                    int* __restrict__ counts,
                                                    int* __restrict__ offp) {
  const int e = blockIdx.x;
  const int lane = threadIdx.x;
  int cnt[E];
#pragma unroll
  for (int ee = 0; ee < E; ee++) cnt[ee] = 0;
  for (int idx = lane; idx < 2 * T; idx += 64) {
    int v = tok_e[idx];
#pragma unroll
    for (int ee = 0; ee < E; ee++) cnt[ee] += (v == ee) ? 1 : 0;
  }
#pragma unroll
  for (int ee = 0; ee < E; ee++) {
#pragma unroll
    for (int off = 32; off >= 1; off >>= 1) cnt[ee] += __shfl_xor(cnt[ee], off, 64);
  }
  int off_e[E + 1];
  int o = 0;
#pragma unroll
  for (int ee = 0; ee < E; ee++) { off_e[ee] = o; o += (cnt[ee] + (BM - 1)) & ~(BM - 1); }
  off_e[E] = o;
  if (e == 0 && lane == 0) {
#pragma unroll
    for (int ee = 0; ee < E; ee++) { counts[ee] = cnt[ee]; offp[ee] = off_e[ee]; }
    offp[E] = o;
  }
  int base = 0, mycnt = 0, myend = 0;
#pragma unroll
  for (int ee = 0; ee < E; ee++) {
    if (ee == e) { base = off_e[ee]; mycnt = cnt[ee]; myend = off_e[ee + 1]; }
  }
  const int pad0 = base + mycnt;
  for (int r = 0; r < 2 * T / 64; r++) {
    int idx = r * 64 + lane;
    int v = tok_e[idx];
    bool m = (v == e);
    unsigned long long mask = __ballot(m);
    int pre = __popcll(mask & ((1ull << lane) - 1ull));
    if (m) {
      int slot = base + pre;
      perm[slot] = idx >> 1;
      slot_of[idx] = slot;
    }
    base += __popcll(mask);
  }
  for (int i = pad0 + lane; i < myend; i += 64) perm[i] = 0;
}

// GEMM1: hbuf[slot][f] = gelu( x[perm[slot]] . w1[e][f] + b1[e][f] ), bf16 out
// 128x128 tile, dbuf, 4 blocks/CU (launch_bounds(256,4) -> VGPR 64, verified R6:
// occupancy 32->42%, gemm1 226->214 us). XCD-chunked (8 x 544) quarter-walk.
// Blocks [4352, 20736): fp32->bf16 cast of w2 (backfills free CU slots + drain
// tail; measured free in R6 — same dur as without the cast).
__global__ __launch_bounds__(256, 4) void gemm1_kernel(const unsigned short* __restrict__ xg,
                                                       const unsigned short* __restrict__ w1g,
                                                       const float* __restrict__ b1,
                                                       const int* __restrict__ perm,
                                                       const int* __restrict__ offp,
                                                       const int* __restrict__ counts,
                                                       unsigned short* __restrict__ hbuf,
                                                       const float* __restrict__ w2,
                                                       unsigned short* __restrict__ w2g) {
  const int id = blockIdx.x;
  if (id >= 4352) {                              // trailing w2-cast blocks
    int i = (id - 4352) * 256 + threadIdx.x;     // [0, E*D*F/8)
    const float4* p = (const float4*)w2 + (size_t)i * 2;
    float4 a = p[0], b = p[1];
    u16x8 o;
    o[0] = f2bf(a.x); o[1] = f2bf(a.y); o[2] = f2bf(a.z); o[3] = f2bf(a.w);
    o[4] = f2bf(b.x); o[5] = f2bf(b.y); o[6] = f2bf(b.z); o[7] = f2bf(b.w);
    *(u16x8*)(w2g + (size_t)i * 8) = o;
    return;
  }
  const int xcd = id & 7, loc = id >> 3;        // loc in [0,544)
  const int q = loc / 136, r = loc % 136;       // 4 quarters x (17bm x 8bn)
  const int bm = xcd * 17 + (r >> 3);
  const int bn = q * 8 + (r & 7);
  const int row0 = bm * BM;
  if (row0 >= offp[E]) return;
  int e = 0;
#pragma unroll
  for (int i = 0; i < E; i++) if (row0 >= offp[i + 1]) e = i + 1;
  if (row0 >= offp[e] + counts[e]) return;  // block entirely padding

  const int tid = threadIdx.x, lane = tid & 63, w = tid >> 6;
  __shared__ __align__(16) unsigned short smem[BM * EP_STRIDE];
  unsigned short* As0 = smem;            // As[buf] = As0 + buf*4096
  unsigned short* Bs0 = smem + 8192;     // Bs[buf] = Bs0 + buf*4096

  const unsigned short* gsrc[4];
  unsigned short* ldst[4];
#pragma unroll
  for (int i = 0; i < 4; i++) {
    int ch = tid + 256 * i;
    if (ch < 512) {
      int ar = ch >> 2, ac = (ch & 3) * 8;
      gsrc[i] = xg + (size_t)perm[row0 + ar] * D + ac;
      ldst[i] = As0 + ch * 8;
    } else {
      int c = ch - 512;
      int br = c >> 2, bc = (c & 3) * 8;
      gsrc[i] = w1g + ((size_t)e * F + (size_t)bn * BM + br) * D + bc;
      ldst[i] = Bs0 + c * 8;
    }
  }
  auto stage = [&](int k0, int buf) {
#pragma unroll
    for (int i = 0; i < 4; i++) gload16(gsrc[i] + k0, ldst[i] + buf * (BM * BK));
  };

  f32x4 acc[4][4] = {};
  const int wr = (w >> 1) * 64, wc = (w & 1) * 64;
  const int fr = lane & 15, fq = lane >> 4;

  stage(0, 0);
  __syncthreads();
  int cur = 0;
  for (int k0 = 0; k0 < D; k0 += BK) {
    if (k0 + BK < D) stage(k0 + BK, cur ^ 1);   // prefetch flies during compute
    bf16x8 a[4], b[4];
#pragma unroll
    for (int m = 0; m < 4; m++) a[m] = *(const bf16x8*)&As0[cur * 4096 + (wr + m * 16 + fr) * BK + fq * 8];
#pragma unroll
    for (int n = 0; n < 4; n++) b[n] = *(const bf16x8*)&Bs0[cur * 4096 + (wc + n * 16 + fr) * BK + fq * 8];
#pragma unroll
    for (int m = 0; m < 4; m++)
#pragma unroll
      for (int n = 0; n < 4; n++)
        acc[m][n] = __builtin_amdgcn_mfma_f32_16x16x32_bf16(a[m], b[n], acc[m][n], 0, 0, 0);
    __syncthreads();
    cur ^= 1;
  }

  // epilogue: bias+gelu in-register -> bf16 LDS tile -> coalesced 16B/lane stores
#pragma unroll
  for (int n = 0; n < 4; n++) {
    int cl = wc + n * 16 + fr;
    float bias = b1[e * F + bn * BM + cl];
#pragma unroll
    for (int m = 0; m < 4; m++) {
#pragma unroll
      for (int j = 0; j < 4; j++) {
        int rl = wr + m * 16 + fq * 4 + j;
        smem[rl * EP_STRIDE + cl] = f2bf(gelu_f(acc[m][n][j] + bias));
      }
    }
  }
  __syncthreads();
#pragma unroll
  for (int i = 0; i < 8; i++) {
    int idx = tid + i * 256;          // 2048 16B-chunks: 128 rows x 16
    int r2 = idx >> 4, c = (idx & 15) * 8;
    u16x8 v = *(const u16x8*)&smem[r2 * EP_STRIDE + c];
    *(u16x8*)&hbuf[(size_t)(row0 + r2) * F + bn * BM + c] = v;
  }
}

// GEMM2 (K-split-2): ypart[ks][slot][d] = h[slot][ks*2048:+2048].w2[e][d][same] (+b2 if ks==0)
// 128x128 tile, dbuf, 4 blocks/CU. Grid 2176 = 8bn x 2ks x 136bm = 8*272.
// R8 lesson: K-split-4 + un-aliased ypart grew the live working set past L3
// (437 MB > 256 MB) and FETCH ballooned to 546 MB — keep K-split-2 + alias.
__global__ __launch_bounds__(256, 4) void gemm2_kernel(const unsigned short* __restrict__ hbuf,
                                                       const unsigned short* __restrict__ w2g,
                                                       const float* __restrict__ b2,
                                                       const int* __restrict__ offp,
                                                       const int* __restrict__ counts,
                                                       unsigned short* __restrict__ ypart) {
  const int id = blockIdx.x;
  const int swz = (id & 7) * 272 + (id >> 3);   // bijective (2176=8*272)
  const int bn = swz & 7;                        // bn fastest -> share A panel
  const int ks = (swz >> 3) & 1;
  const int bm = swz >> 4;
  const int row0 = bm * BM;
  if (row0 >= offp[E]) return;
  int e = 0;
#pragma unroll
  for (int i = 0; i < E; i++) if (row0 >= offp[i + 1]) e = i + 1;
  const int valid_end = offp[e] + counts[e];
  if (row0 >= valid_end) return;

  const int tid = threadIdx.x, lane = tid & 63, w = tid >> 6;
  __shared__ __align__(16) unsigned short smem[BM * EP_STRIDE];
  unsigned short* As0 = smem;
  unsigned short* Bs0 = smem + 8192;

  const int kbase = ks * (F / 2);
  const unsigned short* gsrc[4];
  unsigned short* ldst[4];
#pragma unroll
  for (int i = 0; i < 4; i++) {
    int ch = tid + 256 * i;
    if (ch < 512) {
      int ar = ch >> 2, ac = (ch & 3) * 8;
      gsrc[i] = hbuf + (size_t)(row0 + ar) * F + kbase + ac;
      ldst[i] = As0 + ch * 8;
    } else {
      int c = ch - 512;
      int br = c >> 2, bc = (c & 3) * 8;
      gsrc[i] = w2g + ((size_t)e * D + (size_t)bn * BM + br) * F + kbase + bc;
      ldst[i] = Bs0 + c * 8;
    }
  }
  auto stage = [&](int k0, int buf) {
#pragma unroll
    for (int i = 0; i < 4; i++) gload16(gsrc[i] + k0, ldst[i] + buf * (BM * BK));
  };

  f32x4 acc[4][4] = {};
  const int wr = (w >> 1) * 64, wc = (w & 1) * 64;
  const int fr = lane & 15, fq = lane >> 4;

  stage(0, 0);
  __syncthreads();
  int cur = 0;
  for (int k0 = 0; k0 < F / 2; k0 += BK) {
    if (k0 + BK < F / 2) stage(k0 + BK, cur ^ 1);
    bf16x8 a[4], b[4];
#pragma unroll
    for (int m = 0; m < 4; m++) a[m] = *(const bf16x8*)&As0[cur * 4096 + (wr + m * 16 + fr) * BK + fq * 8];
#pragma unroll
    for (int n = 0; n < 4; n++) b[n] = *(const bf16x8*)&Bs0[cur * 4096 + (wc + n * 16 + fr) * BK + fq * 8];
#pragma unroll
    for (int m = 0; m < 4; m++)
#pragma unroll
      for (int n = 0; n < 4; n++)
        acc[m][n] = __builtin_amdgcn_mfma_f32_16x16x32_bf16(a[m], b[n], acc[m][n], 0, 0, 0);
    __syncthreads();
    cur ^= 1;
  }

  // epilogue via LDS (full-line coalesced stores)
#pragma unroll
  for (int n = 0; n < 4; n++) {
    int cl = wc + n * 16 + fr;
    float bias = (ks == 0) ? b2[e * D + bn * BM + cl] : 0.0f;
#pragma unroll
    for (int m = 0; m < 4; m++) {
#pragma unroll
      for (int j = 0; j < 4; j++) {
        int rl = wr + m * 16 + fq * 4 + j;
        smem[rl * EP_STRIDE + cl] = f2bf(acc[m][n][j] + bias);
      }
    }
  }
  __syncthreads();
  unsigned short* ybase = ypart + (size_t)ks * SLOT_CAP * D;
#pragma unroll
  for (int i = 0; i < 8; i++) {
    int idx = tid + i * 256;
    int r2 = idx >> 4, c = (idx & 15) * 8;
    if (row0 + r2 < valid_end) {
      u16x8 v = *(const u16x8*)&smem[r2 * EP_STRIDE + c];
      *(u16x8*)&ybase[(size_t)(row0 + r2) * D + bn * BM + c] = v;
    }
  }
}

// out[t][d] = g0*(p0[s0]+p1[s0]) + g1*(p0[s1]+p1[s1])   (full overwrite -> no memset)
__global__ __launch_bounds__(256) void combine_kernel(const unsigned short* __restrict__ ypart,
                                                      const int* __restrict__ slot_of,
                                                      const float* __restrict__ tok_p,
                                                      float* __restrict__ out) {
  int i = blockIdx.x * 256 + threadIdx.x;   // indexes 8-elem groups
  int t = i >> 7;                            // D/8 = 128 groups per token
  int g8 = i & 127;
  int s0 = slot_of[2 * t], s1 = slot_of[2 * t + 1];
  float g0 = tok_p[2 * t], g1 = tok_p[2 * t + 1];
  const unsigned short* p0 = ypart;
  const unsigned short* p1 = ypart + (size_t)SLOT_CAP * D;
  u16x8 a0 = *(const u16x8*)(p0 + (size_t)s0 * D + g8 * 8);
  u16x8 b0 = *(const u16x8*)(p1 + (size_t)s0 * D + g8 * 8);
  u16x8 a1 = *(const u16x8*)(p0 + (size_t)s1 * D + g8 * 8);
  u16x8 b1 = *(const u16x8*)(p1 + (size_t)s1 * D + g8 * 8);
  float o[8];
#pragma unroll
  for (int j = 0; j < 8; j++)
    o[j] = g0 * (bf2f(a0[j]) + bf2f(b0[j])) + g1 * (bf2f(a1[j]) + bf2f(b1[j]));
  float4* op = (float4*)(out + (size_t)t * D + g8 * 8);
  op[0] = make_float4(o[0], o[1], o[2], o[3]);
  op[1] = make_float4(o[4], o[5], o[6], o[7]);
}

extern "C" void kernel_launch(void* const* d_in, const int* in_sizes, int n_in,
                              void* d_out, int out_size, void* d_ws, size_t ws_size,
                              hipStream_t stream) {
  const float* x = (const float*)d_in[0];
  const float* rw = (const float*)d_in[1];
  const float* w1 = (const float*)d_in[2];
  const float* b1 = (const float*)d_in[3];
  const float* w2 = (const float*)d_in[4];
  const float* b2 = (const float*)d_in[5];
  float* out = (float*)d_out;

  char* ws = (char*)d_ws;
  size_t off = 0;
  auto alloc = [&](size_t bytes) {
    void* p = ws + off;
    off = (off + bytes + 255) & ~(size_t)255;
    return p;
  };
  int* counts = (int*)alloc(E * 4);
  int* offp = (int*)alloc((E + 1) * 4);
  int* tok_e = (int*)alloc((size_t)T * 2 * 4);
  float* tok_p = (float*)alloc((size_t)T * 2 * 4);
  int* perm = (int*)alloc((size_t)SLOT_CAP * 4);
  int* slot_of = (int*)alloc((size_t)T * 2 * 4);
  unsigned short* xg = (unsigned short*)alloc((size_t)T * D * 2);        // 16.8 MB
  unsigned short* w1g = (unsigned short*)alloc((size_t)E * F * D * 2);   // 67 MB
  unsigned short* w2g = (unsigned short*)alloc((size_t)E * D * F * 2);   // 67 MB
  unsigned short* hbuf = (unsigned short*)alloc((size_t)SLOT_CAP * F * 2); // 143 MB
  // ypart: 2 bf16 partial buffers, 71.3 MB, aliased over xg(16.8)+w1g(67)
  // (dead after gemm1; re-written by prep every call -> deterministic).
  // R8 lesson: this alias keeps the live working set L3-resident — keep it.
  unsigned short* ypart = xg;
  (void)ws_size; (void)in_sizes; (void)n_in; (void)out_size;

  hipLaunchKernelGGL(prep_kernel, dim3(2048 + E * F * D / 8 / 256), dim3(256), 0, stream,
                     x, rw, w1, tok_e, tok_p, xg, w1g);
  hipLaunchKernelGGL(bucket_kernel, dim3(E), dim3(64), 0, stream,
                     tok_e, perm, slot_of, counts, offp);
  hipLaunchKernelGGL(gemm1_kernel, dim3(4352 + E * D * F / 8 / 256), dim3(256), 0, stream,
                     xg, w1g, b1, perm, offp, counts, hbuf, w2, w2g);
  hipLaunchKernelGGL(gemm2_kernel, dim3(2176), dim3(256), 0, stream,
                     hbuf, w2g, b2, offp, counts, ypart);
  hipLaunchKernelGGL(combine_kernel, dim3(T * D / 8 / 256), dim3(256), 0, stream,
                     ypart, slot_of, tok_p, out);
}